// Round 2
// baseline (80.263 us; speedup 1.0000x reference)
//
#include <hip/hip_runtime.h>

// Problem: A=1, B=32, M=32, H=1024, E=8, N=1024 (all fp32)
// out[b,e] = mask[b,e] * sum_h (sum_m hidden[b,m,h]) * (sum_n weight[e,h,n])
//
// ws layout (floats): [0, E*H)          wsum  (8192)
//                     [E*H, E*H + B*H)  hsum  (32768)

#define Bdim 32
#define Mdim 32
#define Hdim 1024
#define Edim 8
#define Ndim 1024

// Kernel A: both streaming reductions in one launch.
// blocks [0,512): weight rows — 2048 waves, one wave per 4 rows of N=1024,
//                 float4 loads (16 B/lane, 1 KiB per wave-instruction).
// blocks [512,544): hidden M-reduction — thread per (b, h/4), float4 loads,
//                 fully coalesced across h.
__global__ __launch_bounds__(256) void reduce_kernel(
    const float* __restrict__ hidden,   // (B,M,H)
    const float* __restrict__ weight,   // (E,H,N)
    float* __restrict__ ws)
{
    constexpr int NB_W = 512;
    if (blockIdx.x < NB_W) {
        const int wave = blockIdx.x * 4 + (threadIdx.x >> 6);
        const int lane = threadIdx.x & 63;
        const float4* w4 = reinterpret_cast<const float4*>(weight);
        #pragma unroll
        for (int r = 0; r < 4; ++r) {
            const int row = wave * 4 + r;          // row = e*H + h, 0..8191
            float s = 0.f;
            #pragma unroll
            for (int j = 0; j < 4; ++j) {
                float4 v = w4[row * (Ndim / 4) + j * 64 + lane];
                s += (v.x + v.y) + (v.z + v.w);
            }
            #pragma unroll
            for (int off = 32; off > 0; off >>= 1)
                s += __shfl_xor(s, off, 64);
            if (lane == 0) ws[row] = s;
        }
    } else {
        // 32 blocks x 256 threads = 8192 threads = B*H/4
        const int idx = (blockIdx.x - NB_W) * 256 + threadIdx.x; // b*256 + h/4
        const int b = idx >> 8;
        const float4* p4 = reinterpret_cast<const float4*>(hidden) + b * (Mdim * Hdim / 4) + (idx & 255);
        float4 acc = {0.f, 0.f, 0.f, 0.f};
        #pragma unroll
        for (int m = 0; m < Mdim; ++m) {
            float4 v = p4[m * (Hdim / 4)];
            acc.x += v.x; acc.y += v.y; acc.z += v.z; acc.w += v.w;
        }
        reinterpret_cast<float4*>(ws + Edim * Hdim)[idx] = acc;
    }
}

// Kernel B: 256 waves, one per (b,e); dot over h=1024 of hsum[b,:]*wsum[e,:]
// via float4 loads, masked by sparsity[b,e].
__global__ __launch_bounds__(256) void dot_kernel(
    const float* __restrict__ ws,
    const float* __restrict__ sparsity,  // (B,E) flat
    float* __restrict__ out)             // (B,E) flat
{
    const int o = blockIdx.x * 4 + (threadIdx.x >> 6);   // b*E + e, 0..255
    const int lane = threadIdx.x & 63;
    const int b = o >> 3;
    const int e = o & 7;
    const float4* hsum4 = reinterpret_cast<const float4*>(ws + Edim * Hdim + b * Hdim);
    const float4* wsum4 = reinterpret_cast<const float4*>(ws + e * Hdim);
    float s = 0.f;
    #pragma unroll
    for (int j = 0; j < 4; ++j) {
        const int h4 = j * 64 + lane;
        float4 a = hsum4[h4];
        float4 w = wsum4[h4];
        s += a.x * w.x + a.y * w.y + a.z * w.z + a.w * w.w;
    }
    #pragma unroll
    for (int off = 32; off > 0; off >>= 1)
        s += __shfl_xor(s, off, 64);
    if (lane == 0) out[o] = s * sparsity[o];
}

extern "C" void kernel_launch(void* const* d_in, const int* in_sizes, int n_in,
                              void* d_out, int out_size, void* d_ws, size_t ws_size,
                              hipStream_t stream) {
    const float* hidden   = (const float*)d_in[0];  // (1,32,32,1024)
    const float* sparsity = (const float*)d_in[1];  // (1,32,1,8)
    const float* weight   = (const float*)d_in[2];  // (1,8,1024,1024)
    float* out = (float*)d_out;                     // (1,32,8)
    float* ws  = (float*)d_ws;

    reduce_kernel<<<544, 256, 0, stream>>>(hidden, weight, ws);
    dot_kernel<<<64, 256, 0, stream>>>(ws, sparsity, out);
}